// Round 1
// 678.477 us; speedup vs baseline: 1.0831x; 1.0831x over previous
//
#include <hip/hip_runtime.h>
#include <hip/hip_bf16.h>

// MHAGCN: x(4096,6,1024) f32 -> out(4096,6,256) f32. Internal bf16 + MFMA.
// R7: replace the m97-structure 128x128 2-barrier GEMM with the verified
// 256x256 8-phase template (T2 swizzle + T3/T4 counted vmcnt + T5 setprio).
// BK=64, 8 waves (2Mx4N), 128KiB LDS dbuf, half-tile staging via
// global_load_lds (linear dest, inverse-swizzled source), vmcnt(6) once per
// K-tile. Old 128^2 kernel kept for the small-workspace fallback path.

using bf16 = __hip_bfloat16;
using s16x8 = __attribute__((ext_vector_type(8))) short;
using f32x4 = __attribute__((ext_vector_type(4))) float;

#define AS1(p) ((__attribute__((address_space(1))) void*)((void*)(p)))
#define AS3(p) ((__attribute__((address_space(3))) void*)(p))

#if defined(__has_builtin)
#if __has_builtin(__builtin_amdgcn_global_load_lds)
#define HAVE_GLL 1
#endif
#endif

__device__ __forceinline__ float s2f(short s) {
  union { unsigned int u; float f; } c;
  c.u = ((unsigned int)(unsigned short)s) << 16;
  return c.f;
}
__device__ __forceinline__ short f2s(float x) {
  bf16 b = __float2bfloat16(x);
  short s;
  __builtin_memcpy(&s, &b, 2);
  return s;
}

// ---------------------------------------------------------------------------
// x (f32) -> bf16, 8 els/thread
// ---------------------------------------------------------------------------
__global__ void cvt_f32_bf16(const float* __restrict__ in, bf16* __restrict__ out, int n8) {
  int i = blockIdx.x * blockDim.x + threadIdx.x;
  if (i >= n8) return;
  float4 p0 = ((const float4*)in)[i * 2];
  float4 p1 = ((const float4*)in)[i * 2 + 1];
  s16x8 v;
  v[0] = f2s(p0.x); v[1] = f2s(p0.y); v[2] = f2s(p0.z); v[3] = f2s(p0.w);
  v[4] = f2s(p1.x); v[5] = f2s(p1.y); v[6] = f2s(p1.z); v[7] = f2s(p1.w);
  ((s16x8*)out)[i] = v;
}

// ---------------------------------------------------------------------------
// Transpose f32 (R x C) -> bf16 (C x R); one matrix per blockIdx.z
// ---------------------------------------------------------------------------
__global__ void transpose_f2b(const float* __restrict__ in, bf16* __restrict__ out,
                              int R, int C) {
  __shared__ short tile[32][33];
  const float* src = in + (size_t)blockIdx.z * R * C;
  short* dst = (short*)out + (size_t)blockIdx.z * R * C;
  int r0 = blockIdx.x * 32, c0 = blockIdx.y * 32;
  int tx = threadIdx.x, ty = threadIdx.y;  // (32, 8)
#pragma unroll
  for (int i = 0; i < 4; ++i)
    tile[ty + i * 8][tx] = f2s(src[(size_t)(r0 + ty + i * 8) * C + c0 + tx]);
  __syncthreads();
#pragma unroll
  for (int i = 0; i < 4; ++i)
    dst[(size_t)(c0 + ty + i * 8) * R + r0 + tx] = tile[tx][ty + i * 8];
}

// ---------------------------------------------------------------------------
// Legacy 128x128 GEMM (m97 structure) — kept for the !big fallback path.
// ---------------------------------------------------------------------------
template <int AF32>
__global__ __launch_bounds__(256) void gemm_bt(
    const void* __restrict__ Ag,
    const bf16* __restrict__ Bt0, const bf16* __restrict__ Bt1,
    const float* __restrict__ bias0, const float* __restrict__ bias1, int boff,
    bf16* __restrict__ out0, bf16* __restrict__ out1,
    int M, int N, int K) {
  const bf16* Bt = (blockIdx.z == 0) ? Bt0 : Bt1;
  const float* bias = (blockIdx.z == 0) ? bias0 : bias1;
  bf16* Cg = (blockIdx.z == 0) ? out0 : out1;

  __shared__ short lA[128 * 32];
  __shared__ short lB[128 * 32];

  const int tid = threadIdx.x;
  const int lane = tid & 63, w = tid >> 6;
  const int wr = w >> 1, wc = w & 1;
  const int l16 = lane & 15, quad = lane >> 4;
  const int lrow = lane >> 2;
  const int scol = (((lane & 3) ^ ((lane >> 3) & 3)) * 8);

  const size_t rm0 = (size_t)blockIdx.x * 128;
  const size_t cn0 = (size_t)blockIdx.y * 128;

  f32x4 acc[4][4];
#pragma unroll
  for (int i = 0; i < 4; ++i)
#pragma unroll
    for (int j = 0; j < 4; ++j) acc[i][j] = (f32x4){0.f, 0.f, 0.f, 0.f};

  for (int kb = 0; kb < K; kb += 32) {
#pragma unroll
    for (int t = 0; t < 2; ++t) {
      int chunk = w * 2 + t;
      int row = chunk * 16 + lrow;
      const bf16* gb = Bt + (cn0 + row) * (size_t)K + kb + scol;
#ifdef HAVE_GLL
      __builtin_amdgcn_global_load_lds(AS1(gb), AS3(lB + chunk * 512), 16, 0, 0);
#else
      *(s16x8*)(lB + chunk * 512 + lane * 8) = *(const s16x8*)gb;
#endif
      if (AF32) {
        const float* ga = (const float*)Ag + (rm0 + row) * (size_t)K + kb + scol;
        float4 p0 = *(const float4*)ga;
        float4 p1 = *(const float4*)(ga + 4);
        s16x8 v;
        v[0] = f2s(p0.x); v[1] = f2s(p0.y); v[2] = f2s(p0.z); v[3] = f2s(p0.w);
        v[4] = f2s(p1.x); v[5] = f2s(p1.y); v[6] = f2s(p1.z); v[7] = f2s(p1.w);
        *(s16x8*)(lA + chunk * 512 + lane * 8) = v;
      } else {
        const bf16* ga = (const bf16*)Ag + (rm0 + row) * (size_t)K + kb + scol;
#ifdef HAVE_GLL
        __builtin_amdgcn_global_load_lds(AS1(ga), AS3(lA + chunk * 512), 16, 0, 0);
#else
        *(s16x8*)(lA + chunk * 512 + lane * 8) = *(const s16x8*)ga;
#endif
      }
    }
    __syncthreads();

    const int q2 = (quad ^ ((l16 >> 1) & 3)) * 8;
    s16x8 af[4], bfv[4];
#pragma unroll
    for (int i = 0; i < 4; ++i) {
      af[i] = *(const s16x8*)(lA + (wr * 64 + i * 16 + l16) * 32 + q2);
      bfv[i] = *(const s16x8*)(lB + (wc * 64 + i * 16 + l16) * 32 + q2);
    }
#pragma unroll
    for (int i = 0; i < 4; ++i)
#pragma unroll
      for (int j = 0; j < 4; ++j)
        acc[i][j] = __builtin_amdgcn_mfma_f32_16x16x32_bf16(af[i], bfv[j], acc[i][j], 0, 0, 0);
    __syncthreads();
  }

#pragma unroll
  for (int j = 0; j < 4; ++j) {
    size_t col = cn0 + wc * 64 + j * 16 + l16;
    float bv = bias ? bias[boff + col] : 0.f;
#pragma unroll
    for (int i = 0; i < 4; ++i) {
      size_t rowb = rm0 + wr * 64 + i * 16 + quad * 4;
#pragma unroll
      for (int r = 0; r < 4; ++r) {
        float v = acc[i][j][r] + bv;
        Cg[(rowb + r) * (size_t)N + col] = __float2bfloat16(v);
      }
    }
  }
}

// ---------------------------------------------------------------------------
// 256x256 8-phase GEMM (m201 template, plain HIP).
// C[M,N](bf16) = A[M,K](bf16) @ Bt[N,K]^T + bias[N](f32).
// 512 threads = 8 waves (2Mx4N), per-wave C block 128x64 (acc f32x4[8][4]).
// LDS 128 KiB: buf{0,1} x [A 256x64 | B 256x64] bf16. BK=64.
// Swizzle: 16B unit u of row r stored at slot u^(r&7) (within the 128B row);
// global_load_lds dest stays linear, source column pre-swizzled (m173).
// Staging: 4 half-tiles (128x64 = 2 gll/thread) per K-tile, one per phase:
//   ph0: next-tile Ah1 (other buf)   ph1: tile+2 Bh0 (this buf, B read-done)
//   ph2: tile+2 Bh1                  ph3: tile+2 Ah0, then vmcnt(6)
// vmcnt(6) = 3 half-tiles in flight; everything older is landed chip-wide
// after the barrier. B fragments for BOTH n-halves are read in ph0 and held
// in registers so B LDS slots are free from ph1 on. Requires K%128==0... no:
// K/64 even and >=2 (K=512,1024 here), M%256==0, N%256==0.
// ---------------------------------------------------------------------------
__global__ __launch_bounds__(512, 2) void gemm256_8ph(
    const bf16* __restrict__ A,
    const bf16* __restrict__ Bt0, const bf16* __restrict__ Bt1,
    const float* __restrict__ bias0, const float* __restrict__ bias1, int boff,
    bf16* __restrict__ out0, bf16* __restrict__ out1,
    int M, int N, int K) {
  const bf16* Bt = (blockIdx.z == 0) ? Bt0 : Bt1;
  const float* bias = (blockIdx.z == 0) ? bias0 : bias1;
  bf16* Cg = (blockIdx.z == 0) ? out0 : out1;

  __shared__ __attribute__((aligned(16))) short ldsS[65536];  // 128 KiB

  const int tid = threadIdx.x;
  const int w = tid >> 6, l = tid & 63;
  const int l16 = l & 15, quad = l >> 4;
  const int wr = w >> 2, wc = w & 3;

  const size_t rm0 = (size_t)blockIdx.x * 256;
  const size_t cn0 = (size_t)blockIdx.y * 256;

  // Staging source (inverse-swizzled column): lane l covers LDS slot
  // row=(w*16+g*8+(l>>3)), unit slot (l&7); content unit = (l&7)^(row&7)
  // and row&7 == l>>3, so colS is the same for every half/g.
  const int colS = ((l & 7) ^ (l >> 3)) * 8;       // shorts
  const int rowS = w * 16 + (l >> 3);              // + g*8 + h*128
  const short* pAs = (const short*)A + (rm0 + rowS) * (size_t)K + colS;
  const short* pBs = (const short*)Bt + (cn0 + rowS) * (size_t)K + colS;

  // Read-side swizzled unit offsets (shorts): unit (kk*4+quad) ^ (l16&7)
  const int u0 = (quad ^ (l16 & 7)) * 8;
  const int u1 = ((quad + 4) ^ (l16 & 7)) * 8;

  f32x4 acc[8][4];
#pragma unroll
  for (int i = 0; i < 8; ++i)
#pragma unroll
    for (int j = 0; j < 4; ++j) acc[i][j] = (f32x4){0.f, 0.f, 0.f, 0.f};

  s16x8 af[4][2], bf0[2][2], bf1[2][2];

  const int T = K >> 6;  // K-tiles of 64

// stage half-tile H (128 rows) of A/B at k-offset KB (shorts) into buffer BUF
#ifdef HAVE_GLL
#define SA(BUF, H, KB) do {                                                          \
    __builtin_amdgcn_global_load_lds(AS1(pAs + (size_t)((H) * 128) * K + (KB)),      \
        AS3(ldsS + (BUF) * 32768 + (H) * 8192 + w * 1024), 16, 0, 0);                \
    __builtin_amdgcn_global_load_lds(AS1(pAs + (size_t)((H) * 128 + 8) * K + (KB)),  \
        AS3(ldsS + (BUF) * 32768 + (H) * 8192 + w * 1024 + 512), 16, 0, 0);          \
  } while (0)
#define SB(BUF, H, KB) do {                                                          \
    __builtin_amdgcn_global_load_lds(AS1(pBs + (size_t)((H) * 128) * K + (KB)),      \
        AS3(ldsS + (BUF) * 32768 + 16384 + (H) * 8192 + w * 1024), 16, 0, 0);        \
    __builtin_amdgcn_global_load_lds(AS1(pBs + (size_t)((H) * 128 + 8) * K + (KB)),  \
        AS3(ldsS + (BUF) * 32768 + 16384 + (H) * 8192 + w * 1024 + 512), 16, 0, 0);  \
  } while (0)
#else
#define SA(BUF, H, KB) do {                                                          \
    *(s16x8*)(ldsS + (BUF) * 32768 + (H) * 8192 + w * 1024 + l * 8) =                \
        *(const s16x8*)(pAs + (size_t)((H) * 128) * K + (KB));                       \
    *(s16x8*)(ldsS + (BUF) * 32768 + (H) * 8192 + w * 1024 + 512 + l * 8) =          \
        *(const s16x8*)(pAs + (size_t)((H) * 128 + 8) * K + (KB));                   \
  } while (0)
#define SB(BUF, H, KB) do {                                                          \
    *(s16x8*)(ldsS + (BUF) * 32768 + 16384 + (H) * 8192 + w * 1024 + l * 8) =        \
        *(const s16x8*)(pBs + (size_t)((H) * 128) * K + (KB));                       \
    *(s16x8*)(ldsS + (BUF) * 32768 + 16384 + (H) * 8192 + w * 1024 + 512 + l * 8) =  \
        *(const s16x8*)(pBs + (size_t)((H) * 128 + 8) * K + (KB));                   \
  } while (0)
#endif

#define LDA(BUF, MH) do {                                                            \
    _Pragma("unroll") for (int i = 0; i < 4; ++i) {                                  \
      const short* bse = ldsS + (BUF) * 32768 + wr * 8192 + (MH) * 4096 +            \
                         i * 1024 + l16 * 64;                                        \
      af[i][0] = *(const s16x8*)(bse + u0);                                          \
      af[i][1] = *(const s16x8*)(bse + u1);                                          \
    }                                                                                \
  } while (0)

#define LDB(BUF, NH, DST) do {                                                       \
    _Pragma("unroll") for (int n = 0; n < 2; ++n) {                                  \
      const short* bse = ldsS + (BUF) * 32768 + 16384 + (wc >> 1) * 8192 +           \
                         (wc & 1) * 4096 + (NH) * 2048 + n * 1024 + l16 * 64;        \
      DST[n][0] = *(const s16x8*)(bse + u0);                                         \
      DST[n][1] = *(const s16x8*)(bse + u1);                                         \
    }                                                                                \
  } while (0)

#define MFMAQ(MH, NH, BSET) do {                                                     \
    _Pragma("unroll") for (int i = 0; i < 4; ++i)                                    \
      _Pragma("unroll") for (int n = 0; n < 2; ++n) {                                \
        acc[(MH) * 4 + i][(NH) * 2 + n] = __builtin_amdgcn_mfma_f32_16x16x32_bf16(   \
            af[i][0], BSET[n][0], acc[(MH) * 4 + i][(NH) * 2 + n], 0, 0, 0);         \
        acc[(MH) * 4 + i][(NH) * 2 + n] = __builtin_amdgcn_mfma_f32_16x16x32_bf16(   \
            af[i][1], BSET[n][1], acc[(MH) * 4 + i][(NH) * 2 + n], 0, 0, 0);         \
      }                                                                              \
  } while (0)

#define BARX() asm volatile("s_barrier" ::: "memory")
#define LGKM0() do { asm volatile("s_waitcnt lgkmcnt(0)" ::: "memory");              \
                     __builtin_amdgcn_sched_barrier(0); } while (0)
#define VM6() do { asm volatile("s_waitcnt vmcnt(6)" ::: "memory");                  \
                   __builtin_amdgcn_sched_barrier(0); } while (0)

#define TILE_STEP(BUF, t) do {                                                       \
    const int kN_ = ((t) + 1 < T ? (t) + 1 : T - 1) << 6;                            \
    const int k2_ = ((t) + 2 < T ? (t) + 2 : T - 1) << 6;                            \
    /* ph0: all A(mh0) + all B reads; stage next tile's Ah1 (other buf) */           \
    LDA(BUF, 0); LDB(BUF, 0, bf0); LDB(BUF, 1, bf1);                                 \
    SA((BUF) ^ 1, 1, kN_);                                                           \
    BARX(); LGKM0();                                                                 \
    __builtin_amdgcn_s_setprio(1); MFMAQ(0, 0, bf0); __builtin_amdgcn_s_setprio(0);  \
    BARX();                                                                          \
    /* ph1: B slots of this buf are read-done -> stage t+2 Bh0 */                    \
    SB(BUF, 0, k2_);                                                                 \
    BARX();                                                                          \
    __builtin_amdgcn_s_setprio(1); MFMAQ(0, 1, bf1); __builtin_amdgcn_s_setprio(0);  \
    BARX();                                                                          \
    /* ph2: A(mh1) reads; stage t+2 Bh1 */                                           \
    LDA(BUF, 1);                                                                     \
    SB(BUF, 1, k2_);                                                                 \
    BARX(); LGKM0();                                                                 \
    __builtin_amdgcn_s_setprio(1); MFMAQ(1, 1, bf1); __builtin_amdgcn_s_setprio(0);  \
    BARX();                                                                          \
    /* ph3: A-half0 read-done -> stage t+2 Ah0; counted drain */                     \
    SA(BUF, 0, k2_);                                                                 \
    VM6();                                                                           \
    BARX();                                                                          \
    __builtin_amdgcn_s_setprio(1); MFMAQ(1, 0, bf0); __builtin_amdgcn_s_setprio(0);  \
    BARX();                                                                          \
  } while (0)

  // prologue: tile0 fully + tile1 {Bh0,Bh1,Ah0}; vmcnt(6) -> tile0 landed
  {
    const int k1_ = (T > 1 ? 1 : 0) << 6;
    SB(0, 0, 0); SB(0, 1, 0); SA(0, 0, 0); SA(0, 1, 0);
    SB(1, 0, k1_); SB(1, 1, k1_); SA(1, 0, k1_);
    VM6();
    BARX();
  }

  for (int t = 0; t < T; t += 2) {
    TILE_STEP(0, t);
    TILE_STEP(1, t + 1);
  }

  // epilogue: D row = quad*4+r, col = l16 (m89-verified layout)
#pragma unroll
  for (int j = 0; j < 4; ++j) {
    size_t col = cn0 + wc * 64 + j * 16 + l16;
    float bv = bias ? bias[boff + col] : 0.f;
#pragma unroll
    for (int i = 0; i < 8; ++i) {
      size_t rowb = rm0 + wr * 128 + i * 16 + quad * 4;
#pragma unroll
      for (int r = 0; r < 4; ++r) {
        Cg[(rowb + r) * (size_t)N + col] = __float2bfloat16(acc[i][j][r] + bv);
      }
    }
  }
#undef SA
#undef SB
#undef LDA
#undef LDB
#undef MFMAQ
#undef BARX
#undef LGKM0
#undef VM6
#undef TILE_STEP
}

// ---------------------------------------------------------------------------
// MFMA scores: per wave, 2 batches packed as rows {b0: 0-7, b1: 8-15} on BOTH
// m and n. Valid outputs are the diagonal blocks only.
// ---------------------------------------------------------------------------
__global__ __launch_bounds__(256) void scores_mfma(
    const bf16* __restrict__ Q, const bf16* __restrict__ KV,
    float* __restrict__ S, int head) {
  const int tid = threadIdx.x;
  const int lane = tid & 63, w = tid >> 6;
  const int l16 = lane & 15, quad = lane >> 4;
  const int b0 = (blockIdx.x * 4 + w) * 2;  // batches b0, b0+1

  int gr = (l16 < 8) ? (b0 * 6 + l16) : ((b0 + 1) * 6 + (l16 - 8));
  if (gr > 24575) gr = 24575;  // clamp padding rows (l16=6,7,14,15 unused)

  const short* qrow = (const short*)Q + (size_t)gr * 512 + quad * 8;
  const short* krow = (const short*)KV + (size_t)gr * 512 + quad * 8;

  f32x4 acc = (f32x4){0.f, 0.f, 0.f, 0.f};
#pragma unroll
  for (int kk = 0; kk < 16; ++kk) {
    s16x8 a = *(const s16x8*)(qrow + kk * 32);
    s16x8 b = *(const s16x8*)(krow + kk * 32);
    acc = __builtin_amdgcn_mfma_f32_16x16x32_bf16(a, b, acc, 0, 0, 0);
  }

  if (l16 < 6) {  // n -> b0 KV rows
#pragma unroll
    for (int r = 0; r < 4; ++r) {
      int m = quad * 4 + r;
      if (m < 6)
        S[((size_t)b0 * 5 + head) * 36 + m * 6 + l16] = acc[r];
    }
  } else if (l16 >= 8 && l16 < 14) {  // n -> b1 KV rows
#pragma unroll
    for (int r = 0; r < 4; ++r) {
      int m = quad * 4 + r;
      if (m >= 8 && m < 14)
        S[((size_t)(b0 + 1) * 5 + head) * 36 + (m - 8) * 6 + (l16 - 8)] = acc[r];
    }
  }
}

// ---------------------------------------------------------------------------
// Per-batch: softmax(scores) -> cat@linW+linb -> softmax -> A;
// h = A@xg + gb1 -> PReLU -> BN1 -> H(bf16). Also store A (f32).
// ---------------------------------------------------------------------------
__global__ void batch_mid_kernel(const float* __restrict__ S, const bf16* __restrict__ XG,
                                 const float* __restrict__ linW, const float* __restrict__ linb,
                                 const float* __restrict__ gb1, const float* __restrict__ prelu,
                                 const float* __restrict__ g1, const float* __restrict__ b1,
                                 const float* __restrict__ m1, const float* __restrict__ v1,
                                 float* __restrict__ Afull, bf16* __restrict__ H) {
  int b = blockIdx.x, tid = threadIdx.x;  // 64 threads
  __shared__ float p[5][6][6];
  __shared__ float Ar[6][6];
  __shared__ float lw[30][6];
  __shared__ float lbv[6];
  __shared__ float sc1[6], sm1[6], sb1[6];

  if (tid < 30) {
    int k = tid / 6, c = tid % 6;
    const float* sp = S + ((size_t)b * 5 + k) * 36 + c * 6;
    float v[6], mx = sp[0];
#pragma unroll
    for (int d = 0; d < 6; ++d) { v[d] = sp[d]; mx = fmaxf(mx, v[d]); }
    float s = 0.f;
#pragma unroll
    for (int d = 0; d < 6; ++d) { v[d] = expf(v[d] - mx); s += v[d]; }
    float inv = 1.f / s;
#pragma unroll
    for (int d = 0; d < 6; ++d) p[k][c][d] = v[d] * inv;
#pragma unroll
    for (int j = 0; j < 6; ++j) lw[tid][j] = linW[tid * 6 + j];
  }
  if (tid < 6) {
    lbv[tid] = linb[tid];
    sc1[tid] = g1[tid] * rsqrtf(v1[tid] + 1e-5f);
    sm1[tid] = m1[tid];
    sb1[tid] = b1[tid];
  }
  __syncthreads();

  if (tid < 6) {
    int c = tid;
    float ap[6];
#pragma unroll
    for (int j = 0; j < 6; ++j) ap[j] = lbv[j];
    for (int k = 0; k < 5; ++k)
#pragma unroll
      for (int d = 0; d < 6; ++d) {
        float pv = p[k][c][d];
#pragma unroll
        for (int j = 0; j < 6; ++j) ap[j] += pv * lw[k * 6 + d][j];
      }
    float mx = ap[0];
#pragma unroll
    for (int j = 1; j < 6; ++j) mx = fmaxf(mx, ap[j]);
    float s = 0.f;
#pragma unroll
    for (int j = 0; j < 6; ++j) { ap[j] = expf(ap[j] - mx); s += ap[j]; }
    float inv = 1.f / s;
#pragma unroll
    for (int j = 0; j < 6; ++j) {
      float a = ap[j] * inv;
      Ar[c][j] = a;
      Afull[(size_t)b * 36 + c * 6 + j] = a;
    }
  }
  __syncthreads();

  float pa = prelu[0];
  for (int col = tid; col < 512; col += 64) {
    float xg[6];
#pragma unroll
    for (int d = 0; d < 6; ++d) xg[d] = s2f(((const short*)XG)[((size_t)b * 6 + d) * 512 + col]);
    float gbv = gb1[col];
#pragma unroll
    for (int c = 0; c < 6; ++c) {
      float h = gbv;
#pragma unroll
      for (int d = 0; d < 6; ++d) h += Ar[c][d] * xg[d];
      h = (h >= 0.f) ? h : pa * h;
      h = (h - sm1[c]) * sc1[c] + sb1[c];
      H[((size_t)b * 6 + c) * 512 + col] = __float2bfloat16(h);
    }
  }
}

// ---------------------------------------------------------------------------
// Per-batch: out(f32) = BN2(A @ hw + gb2)
// ---------------------------------------------------------------------------
__global__ void batch_out_kernel(const float* __restrict__ Afull, const bf16* __restrict__ HW,
                                 const float* __restrict__ gb2,
                                 const float* __restrict__ g2, const float* __restrict__ b2,
                                 const float* __restrict__ m2, const float* __restrict__ v2,
                                 float* __restrict__ out) {
  int b = blockIdx.x, tid = threadIdx.x;  // 64 threads
  __shared__ float Ar[36];
  __shared__ float sc[6], sm[6], sb[6];
  if (tid < 36) Ar[tid] = Afull[(size_t)b * 36 + tid];
  if (tid < 6) {
    sc[tid] = g2[tid] * rsqrtf(v2[tid] + 1e-5f);
    sm[tid] = m2[tid];
    sb[tid] = b2[tid];
  }
  __syncthreads();
  for (int col = tid; col < 256; col += 64) {
    float hw[6];
#pragma unroll
    for (int d = 0; d < 6; ++d) hw[d] = s2f(((const short*)HW)[((size_t)b * 6 + d) * 256 + col]);
    float gv = gb2[col];
#pragma unroll
    for (int c = 0; c < 6; ++c) {
      float o = gv;
#pragma unroll
      for (int d = 0; d < 6; ++d) o += Ar[c * 6 + d] * hw[d];
      o = (o - sm[c]) * sc[c] + sb[c];
      out[((size_t)b * 6 + c) * 256 + col] = o;
    }
  }
}

// ---------------------------------------------------------------------------
extern "C" void kernel_launch(void* const* d_in, const int* in_sizes, int n_in,
                              void* d_out, int out_size, void* d_ws, size_t ws_size,
                              hipStream_t stream) {
  const float* x    = (const float*)d_in[0];
  const float* aW1  = (const float*)d_in[1];
  const float* ab1  = (const float*)d_in[2];
  const float* aW2  = (const float*)d_in[3];
  const float* ab2  = (const float*)d_in[4];
  const float* linW = (const float*)d_in[5];
  const float* linb = (const float*)d_in[6];
  const float* gW1  = (const float*)d_in[7];
  const float* gb1  = (const float*)d_in[8];
  const float* gW2  = (const float*)d_in[9];
  const float* gb2  = (const float*)d_in[10];
  const float* prelu = (const float*)d_in[11];
  const float* bn1g = (const float*)d_in[12];
  const float* bn1b = (const float*)d_in[13];
  const float* bn1m = (const float*)d_in[14];
  const float* bn1v = (const float*)d_in[15];
  const float* bn2g = (const float*)d_in[16];
  const float* bn2b = (const float*)d_in[17];
  const float* bn2m = (const float*)d_in[18];
  const float* bn2v = (const float*)d_in[19];

  char* ws = (char*)d_ws;
  bf16* W1T  = (bf16*)(ws + 0);          // 5 x 512 x 1024
  bf16* W2T  = (bf16*)(ws + 5242880);    // 5 x 512 x 1024
  bf16* G1T  = (bf16*)(ws + 10485760);   // 512 x 1024
  bf16* G2T  = (bf16*)(ws + 11534336);   // 256 x 512
  float* S   = (float*)(ws + 11796480);  // 4096 x 5 x 36
  float* Af  = (float*)(ws + 14745600);  // 4096 x 36
  bf16* BufA = (bf16*)(ws + 15335424);   // 24576 x 512: Q, then XG, then HW
  bf16* BufB = (bf16*)(ws + 40501248);   // 24576 x 512: KV, then H
  bf16* Xb   = (bf16*)(ws + 65667072);   // 24576 x 1024 (optional)
  const bool big = ws_size >= 115998720ull;

  dim3 tb(32, 8);
  transpose_f2b<<<dim3(32, 16, 5), tb, 0, stream>>>(aW1, W1T, 1024, 512);
  transpose_f2b<<<dim3(32, 16, 5), tb, 0, stream>>>(aW2, W2T, 1024, 512);
  transpose_f2b<<<dim3(32, 16, 1), tb, 0, stream>>>(gW1, G1T, 1024, 512);
  transpose_f2b<<<dim3(16, 8, 1),  tb, 0, stream>>>(gW2, G2T, 512, 256);
  if (big) cvt_f32_bf16<<<12288, 256, 0, stream>>>(x, Xb, 3145728);

  // per head: Q,KV GEMM (z=2) then scores
  for (int k = 0; k < 5; ++k) {
    const bf16* w1 = W1T + (size_t)k * 512 * 1024;
    const bf16* w2 = W2T + (size_t)k * 512 * 1024;
    if (big)
      gemm256_8ph<<<dim3(96, 2, 2), 512, 0, stream>>>(
          Xb, w1, w2, ab1, ab2, k * 512, BufA, BufB, 24576, 512, 1024);
    else
      gemm_bt<1><<<dim3(192, 4, 2), 256, 0, stream>>>(
          x, w1, w2, ab1, ab2, k * 512, BufA, BufB, 24576, 512, 1024);
    scores_mfma<<<512, 256, 0, stream>>>(BufA, BufB, S, k);
  }

  // XG = X @ gW1 (Q dead -> BufA)
  if (big)
    gemm256_8ph<<<dim3(96, 2, 1), 512, 0, stream>>>(
        Xb, G1T, G1T, nullptr, nullptr, 0, BufA, BufA, 24576, 512, 1024);
  else
    gemm_bt<1><<<dim3(192, 4, 1), 256, 0, stream>>>(
        x, G1T, G1T, nullptr, nullptr, 0, BufA, BufA, 24576, 512, 1024);

  // softmaxes + A + H (KV dead -> H into BufB)
  batch_mid_kernel<<<4096, 64, 0, stream>>>(S, BufA, linW, linb, gb1, prelu,
                                            bn1g, bn1b, bn1m, bn1v, Af, BufB);

  // HW = H @ gW2 (XG dead -> HW into BufA)
  if (big)
    gemm256_8ph<<<dim3(96, 1, 1), 512, 0, stream>>>(
        BufB, G2T, G2T, nullptr, nullptr, 0, BufA, BufA, 24576, 256, 512);
  else
    gemm_bt<0><<<dim3(192, 2, 1), 256, 0, stream>>>(
        BufB, G2T, G2T, nullptr, nullptr, 0, BufA, BufA, 24576, 256, 512);

  batch_out_kernel<<<4096, 64, 0, stream>>>(Af, BufA, gb2, bn2g, bn2b, bn2m, bn2v,
                                            (float*)d_out);
}

// Round 2
// 631.492 us; speedup vs baseline: 1.1637x; 1.0744x over previous
//
#include <hip/hip_runtime.h>
#include <hip/hip_bf16.h>

// MHAGCN: x(4096,6,1024) f32 -> out(4096,6,256) f32. Internal bf16 + MFMA.
// R8: dispatch-packing. R7 showed per-block rate == m248's known 848 TF for
// this template at K=1024; the loss is grid tails (5 dispatches x 384 blocks
// = 2 rounds @75% fill each, + XG). Pack heads pairwise: grid (96,2,4) =
// 768 blocks = exactly 3 full rounds @100% fill. Last dispatch carries
// head4 Q/KV + XG as z=3. Needs 2 heads' Q/KV live -> +50 MB ws (big2 path,
// falls back to R7 layout if ws < 166 MB). GEMM inner loop untouched.
// HW gemm moved back to legacy 128^2 kernel at (192,2) for better fill.

using bf16 = __hip_bfloat16;
using s16x8 = __attribute__((ext_vector_type(8))) short;
using f32x4 = __attribute__((ext_vector_type(4))) float;

#define AS1(p) ((__attribute__((address_space(1))) void*)((void*)(p)))
#define AS3(p) ((__attribute__((address_space(3))) void*)(p))

#if defined(__has_builtin)
#if __has_builtin(__builtin_amdgcn_global_load_lds)
#define HAVE_GLL 1
#endif
#endif

__device__ __forceinline__ float s2f(short s) {
  union { unsigned int u; float f; } c;
  c.u = ((unsigned int)(unsigned short)s) << 16;
  return c.f;
}
__device__ __forceinline__ short f2s(float x) {
  bf16 b = __float2bfloat16(x);
  short s;
  __builtin_memcpy(&s, &b, 2);
  return s;
}

// GEMM output-routing job (selected per blockIdx.z)
struct GJob {
  const bf16* Bt;
  const float* bias;
  int boff;
  bf16* out;
};

// ---------------------------------------------------------------------------
// x (f32) -> bf16, 8 els/thread
// ---------------------------------------------------------------------------
__global__ void cvt_f32_bf16(const float* __restrict__ in, bf16* __restrict__ out, int n8) {
  int i = blockIdx.x * blockDim.x + threadIdx.x;
  if (i >= n8) return;
  float4 p0 = ((const float4*)in)[i * 2];
  float4 p1 = ((const float4*)in)[i * 2 + 1];
  s16x8 v;
  v[0] = f2s(p0.x); v[1] = f2s(p0.y); v[2] = f2s(p0.z); v[3] = f2s(p0.w);
  v[4] = f2s(p1.x); v[5] = f2s(p1.y); v[6] = f2s(p1.z); v[7] = f2s(p1.w);
  ((s16x8*)out)[i] = v;
}

// ---------------------------------------------------------------------------
// Transpose f32 (R x C) -> bf16 (C x R); one matrix per blockIdx.z
// ---------------------------------------------------------------------------
__global__ void transpose_f2b(const float* __restrict__ in, bf16* __restrict__ out,
                              int R, int C) {
  __shared__ short tile[32][33];
  const float* src = in + (size_t)blockIdx.z * R * C;
  short* dst = (short*)out + (size_t)blockIdx.z * R * C;
  int r0 = blockIdx.x * 32, c0 = blockIdx.y * 32;
  int tx = threadIdx.x, ty = threadIdx.y;  // (32, 8)
#pragma unroll
  for (int i = 0; i < 4; ++i)
    tile[ty + i * 8][tx] = f2s(src[(size_t)(r0 + ty + i * 8) * C + c0 + tx]);
  __syncthreads();
#pragma unroll
  for (int i = 0; i < 4; ++i)
    dst[(size_t)(c0 + ty + i * 8) * R + r0 + tx] = tile[tx][ty + i * 8];
}

// ---------------------------------------------------------------------------
// Legacy 128x128 GEMM (m97 structure) — small-ws fallback + the HW gemm
// (N=256: 128^2 tiles give (192,2)=384 blocks vs 96 for 256^2 -> better fill).
// ---------------------------------------------------------------------------
template <int AF32>
__global__ __launch_bounds__(256) void gemm_bt(
    const void* __restrict__ Ag,
    const bf16* __restrict__ Bt0, const bf16* __restrict__ Bt1,
    const float* __restrict__ bias0, const float* __restrict__ bias1, int boff,
    bf16* __restrict__ out0, bf16* __restrict__ out1,
    int M, int N, int K) {
  const bf16* Bt = (blockIdx.z == 0) ? Bt0 : Bt1;
  const float* bias = (blockIdx.z == 0) ? bias0 : bias1;
  bf16* Cg = (blockIdx.z == 0) ? out0 : out1;

  __shared__ short lA[128 * 32];
  __shared__ short lB[128 * 32];

  const int tid = threadIdx.x;
  const int lane = tid & 63, w = tid >> 6;
  const int wr = w >> 1, wc = w & 1;
  const int l16 = lane & 15, quad = lane >> 4;
  const int lrow = lane >> 2;
  const int scol = (((lane & 3) ^ ((lane >> 3) & 3)) * 8);

  const size_t rm0 = (size_t)blockIdx.x * 128;
  const size_t cn0 = (size_t)blockIdx.y * 128;

  f32x4 acc[4][4];
#pragma unroll
  for (int i = 0; i < 4; ++i)
#pragma unroll
    for (int j = 0; j < 4; ++j) acc[i][j] = (f32x4){0.f, 0.f, 0.f, 0.f};

  for (int kb = 0; kb < K; kb += 32) {
#pragma unroll
    for (int t = 0; t < 2; ++t) {
      int chunk = w * 2 + t;
      int row = chunk * 16 + lrow;
      const bf16* gb = Bt + (cn0 + row) * (size_t)K + kb + scol;
#ifdef HAVE_GLL
      __builtin_amdgcn_global_load_lds(AS1(gb), AS3(lB + chunk * 512), 16, 0, 0);
#else
      *(s16x8*)(lB + chunk * 512 + lane * 8) = *(const s16x8*)gb;
#endif
      if (AF32) {
        const float* ga = (const float*)Ag + (rm0 + row) * (size_t)K + kb + scol;
        float4 p0 = *(const float4*)ga;
        float4 p1 = *(const float4*)(ga + 4);
        s16x8 v;
        v[0] = f2s(p0.x); v[1] = f2s(p0.y); v[2] = f2s(p0.z); v[3] = f2s(p0.w);
        v[4] = f2s(p1.x); v[5] = f2s(p1.y); v[6] = f2s(p1.z); v[7] = f2s(p1.w);
        *(s16x8*)(lA + chunk * 512 + lane * 8) = v;
      } else {
        const bf16* ga = (const bf16*)Ag + (rm0 + row) * (size_t)K + kb + scol;
#ifdef HAVE_GLL
        __builtin_amdgcn_global_load_lds(AS1(ga), AS3(lA + chunk * 512), 16, 0, 0);
#else
        *(s16x8*)(lA + chunk * 512 + lane * 8) = *(const s16x8*)ga;
#endif
      }
    }
    __syncthreads();

    const int q2 = (quad ^ ((l16 >> 1) & 3)) * 8;
    s16x8 af[4], bfv[4];
#pragma unroll
    for (int i = 0; i < 4; ++i) {
      af[i] = *(const s16x8*)(lA + (wr * 64 + i * 16 + l16) * 32 + q2);
      bfv[i] = *(const s16x8*)(lB + (wc * 64 + i * 16 + l16) * 32 + q2);
    }
#pragma unroll
    for (int i = 0; i < 4; ++i)
#pragma unroll
      for (int j = 0; j < 4; ++j)
        acc[i][j] = __builtin_amdgcn_mfma_f32_16x16x32_bf16(af[i], bfv[j], acc[i][j], 0, 0, 0);
    __syncthreads();
  }

#pragma unroll
  for (int j = 0; j < 4; ++j) {
    size_t col = cn0 + wc * 64 + j * 16 + l16;
    float bv = bias ? bias[boff + col] : 0.f;
#pragma unroll
    for (int i = 0; i < 4; ++i) {
      size_t rowb = rm0 + wr * 64 + i * 16 + quad * 4;
#pragma unroll
      for (int r = 0; r < 4; ++r) {
        float v = acc[i][j][r] + bv;
        Cg[(rowb + r) * (size_t)N + col] = __float2bfloat16(v);
      }
    }
  }
}

// ---------------------------------------------------------------------------
// 256x256 8-phase GEMM (m201 template, plain HIP). Inner loop identical to
// R7 (verified); only output routing changed to per-z GJob selection so one
// dispatch can carry up to 4 independent B/out panels over the shared A.
// ---------------------------------------------------------------------------
__global__ __launch_bounds__(512, 2) void gemm256_8ph(
    const bf16* __restrict__ A,
    GJob j0, GJob j1, GJob j2, GJob j3,
    int M, int N, int K) {
  const GJob j = (blockIdx.z == 0) ? j0 : (blockIdx.z == 1) ? j1
               : (blockIdx.z == 2) ? j2 : j3;
  const bf16* Bt = j.Bt;
  const float* bias = j.bias;
  const int boff = j.boff;
  bf16* Cg = j.out;

  __shared__ __attribute__((aligned(16))) short ldsS[65536];  // 128 KiB

  const int tid = threadIdx.x;
  const int w = tid >> 6, l = tid & 63;
  const int l16 = l & 15, quad = l >> 4;
  const int wr = w >> 2, wc = w & 3;

  const size_t rm0 = (size_t)blockIdx.x * 256;
  const size_t cn0 = (size_t)blockIdx.y * 256;

  const int colS = ((l & 7) ^ (l >> 3)) * 8;       // shorts
  const int rowS = w * 16 + (l >> 3);              // + g*8 + h*128
  const short* pAs = (const short*)A + (rm0 + rowS) * (size_t)K + colS;
  const short* pBs = (const short*)Bt + (cn0 + rowS) * (size_t)K + colS;

  const int u0 = (quad ^ (l16 & 7)) * 8;
  const int u1 = ((quad + 4) ^ (l16 & 7)) * 8;

  f32x4 acc[8][4];
#pragma unroll
  for (int i = 0; i < 8; ++i)
#pragma unroll
    for (int j2i = 0; j2i < 4; ++j2i) acc[i][j2i] = (f32x4){0.f, 0.f, 0.f, 0.f};

  s16x8 af[4][2], bf0[2][2], bf1[2][2];

  const int T = K >> 6;  // K-tiles of 64

#ifdef HAVE_GLL
#define SA(BUF, H, KB) do {                                                          \
    __builtin_amdgcn_global_load_lds(AS1(pAs + (size_t)((H) * 128) * K + (KB)),      \
        AS3(ldsS + (BUF) * 32768 + (H) * 8192 + w * 1024), 16, 0, 0);                \
    __builtin_amdgcn_global_load_lds(AS1(pAs + (size_t)((H) * 128 + 8) * K + (KB)),  \
        AS3(ldsS + (BUF) * 32768 + (H) * 8192 + w * 1024 + 512), 16, 0, 0);          \
  } while (0)
#define SB(BUF, H, KB) do {                                                          \
    __builtin_amdgcn_global_load_lds(AS1(pBs + (size_t)((H) * 128) * K + (KB)),      \
        AS3(ldsS + (BUF) * 32768 + 16384 + (H) * 8192 + w * 1024), 16, 0, 0);        \
    __builtin_amdgcn_global_load_lds(AS1(pBs + (size_t)((H) * 128 + 8) * K + (KB)),  \
        AS3(ldsS + (BUF) * 32768 + 16384 + (H) * 8192 + w * 1024 + 512), 16, 0, 0);  \
  } while (0)
#else
#define SA(BUF, H, KB) do {                                                          \
    *(s16x8*)(ldsS + (BUF) * 32768 + (H) * 8192 + w * 1024 + l * 8) =                \
        *(const s16x8*)(pAs + (size_t)((H) * 128) * K + (KB));                       \
    *(s16x8*)(ldsS + (BUF) * 32768 + (H) * 8192 + w * 1024 + 512 + l * 8) =          \
        *(const s16x8*)(pAs + (size_t)((H) * 128 + 8) * K + (KB));                   \
  } while (0)
#define SB(BUF, H, KB) do {                                                          \
    *(s16x8*)(ldsS + (BUF) * 32768 + 16384 + (H) * 8192 + w * 1024 + l * 8) =        \
        *(const s16x8*)(pBs + (size_t)((H) * 128) * K + (KB));                       \
    *(s16x8*)(ldsS + (BUF) * 32768 + 16384 + (H) * 8192 + w * 1024 + 512 + l * 8) =  \
        *(const s16x8*)(pBs + (size_t)((H) * 128 + 8) * K + (KB));                   \
  } while (0)
#endif

#define LDA(BUF, MH) do {                                                            \
    _Pragma("unroll") for (int i = 0; i < 4; ++i) {                                  \
      const short* bse = ldsS + (BUF) * 32768 + wr * 8192 + (MH) * 4096 +            \
                         i * 1024 + l16 * 64;                                        \
      af[i][0] = *(const s16x8*)(bse + u0);                                          \
      af[i][1] = *(const s16x8*)(bse + u1);                                          \
    }                                                                                \
  } while (0)

#define LDB(BUF, NH, DST) do {                                                       \
    _Pragma("unroll") for (int n = 0; n < 2; ++n) {                                  \
      const short* bse = ldsS + (BUF) * 32768 + 16384 + (wc >> 1) * 8192 +           \
                         (wc & 1) * 4096 + (NH) * 2048 + n * 1024 + l16 * 64;        \
      DST[n][0] = *(const s16x8*)(bse + u0);                                         \
      DST[n][1] = *(const s16x8*)(bse + u1);                                         \
    }                                                                                \
  } while (0)

#define MFMAQ(MH, NH, BSET) do {                                                     \
    _Pragma("unroll") for (int i = 0; i < 4; ++i)                                    \
      _Pragma("unroll") for (int n = 0; n < 2; ++n) {                                \
        acc[(MH) * 4 + i][(NH) * 2 + n] = __builtin_amdgcn_mfma_f32_16x16x32_bf16(   \
            af[i][0], BSET[n][0], acc[(MH) * 4 + i][(NH) * 2 + n], 0, 0, 0);         \
        acc[(MH) * 4 + i][(NH) * 2 + n] = __builtin_amdgcn_mfma_f32_16x16x32_bf16(   \
            af[i][1], BSET[n][1], acc[(MH) * 4 + i][(NH) * 2 + n], 0, 0, 0);         \
      }                                                                              \
  } while (0)

#define BARX() asm volatile("s_barrier" ::: "memory")
#define LGKM0() do { asm volatile("s_waitcnt lgkmcnt(0)" ::: "memory");              \
                     __builtin_amdgcn_sched_barrier(0); } while (0)
#define VM6() do { asm volatile("s_waitcnt vmcnt(6)" ::: "memory");                  \
                   __builtin_amdgcn_sched_barrier(0); } while (0)

#define TILE_STEP(BUF, t) do {                                                       \
    const int kN_ = ((t) + 1 < T ? (t) + 1 : T - 1) << 6;                            \
    const int k2_ = ((t) + 2 < T ? (t) + 2 : T - 1) << 6;                            \
    /* ph0: all A(mh0) + all B reads; stage next tile's Ah1 (other buf) */           \
    LDA(BUF, 0); LDB(BUF, 0, bf0); LDB(BUF, 1, bf1);                                 \
    SA((BUF) ^ 1, 1, kN_);                                                           \
    BARX(); LGKM0();                                                                 \
    __builtin_amdgcn_s_setprio(1); MFMAQ(0, 0, bf0); __builtin_amdgcn_s_setprio(0);  \
    BARX();                                                                          \
    /* ph1: B slots of this buf are read-done -> stage t+2 Bh0 */                    \
    SB(BUF, 0, k2_);                                                                 \
    BARX();                                                                          \
    __builtin_amdgcn_s_setprio(1); MFMAQ(0, 1, bf1); __builtin_amdgcn_s_setprio(0);  \
    BARX();                                                                          \
    /* ph2: A(mh1) reads; stage t+2 Bh1 */                                           \
    LDA(BUF, 1);                                                                     \
    SB(BUF, 1, k2_);                                                                 \
    BARX(); LGKM0();                                                                 \
    __builtin_amdgcn_s_setprio(1); MFMAQ(1, 1, bf1); __builtin_amdgcn_s_setprio(0);  \
    BARX();                                                                          \
    /* ph3: A-half0 read-done -> stage t+2 Ah0; counted drain */                     \
    SA(BUF, 0, k2_);                                                                 \
    VM6();                                                                           \
    BARX();                                                                          \
    __builtin_amdgcn_s_setprio(1); MFMAQ(1, 0, bf0); __builtin_amdgcn_s_setprio(0);  \
    BARX();                                                                          \
  } while (0)

  // prologue: tile0 fully + tile1 {Bh0,Bh1,Ah0}; vmcnt(6) -> tile0 landed
  {
    const int k1_ = (T > 1 ? 1 : 0) << 6;
    SB(0, 0, 0); SB(0, 1, 0); SA(0, 0, 0); SA(0, 1, 0);
    SB(1, 0, k1_); SB(1, 1, k1_); SA(1, 0, k1_);
    VM6();
    BARX();
  }

  for (int t = 0; t < T; t += 2) {
    TILE_STEP(0, t);
    TILE_STEP(1, t + 1);
  }

  // epilogue: D row = quad*4+r, col = l16 (m89-verified layout)
#pragma unroll
  for (int jj = 0; jj < 4; ++jj) {
    size_t col = cn0 + wc * 64 + jj * 16 + l16;
    float bv = bias ? bias[boff + col] : 0.f;
#pragma unroll
    for (int i = 0; i < 8; ++i) {
      size_t rowb = rm0 + wr * 128 + i * 16 + quad * 4;
#pragma unroll
      for (int r = 0; r < 4; ++r) {
        Cg[(rowb + r) * (size_t)N + col] = __float2bfloat16(acc[i][jj][r] + bv);
      }
    }
  }
#undef SA
#undef SB
#undef LDA
#undef LDB
#undef MFMAQ
#undef BARX
#undef LGKM0
#undef VM6
#undef TILE_STEP
}

// ---------------------------------------------------------------------------
// MFMA scores, up to 2 heads per launch (blockIdx.y selects head slot).
// Per wave, 2 batches packed as rows {b0: 0-7, b1: 8-15} on BOTH m and n.
// Valid outputs are the diagonal blocks only.
// ---------------------------------------------------------------------------
__global__ __launch_bounds__(256) void scores_mfma2(
    const bf16* __restrict__ Q0, const bf16* __restrict__ KV0,
    const bf16* __restrict__ Q1, const bf16* __restrict__ KV1,
    float* __restrict__ S, int head0) {
  const int h = blockIdx.y;
  const bf16* Q = h ? Q1 : Q0;
  const bf16* KV = h ? KV1 : KV0;
  const int head = head0 + h;

  const int tid = threadIdx.x;
  const int lane = tid & 63, w = tid >> 6;
  const int l16 = lane & 15, quad = lane >> 4;
  const int b0 = (blockIdx.x * 4 + w) * 2;  // batches b0, b0+1

  int gr = (l16 < 8) ? (b0 * 6 + l16) : ((b0 + 1) * 6 + (l16 - 8));
  if (gr > 24575) gr = 24575;  // clamp padding rows (l16=6,7,14,15 unused)

  const short* qrow = (const short*)Q + (size_t)gr * 512 + quad * 8;
  const short* krow = (const short*)KV + (size_t)gr * 512 + quad * 8;

  f32x4 acc = (f32x4){0.f, 0.f, 0.f, 0.f};
#pragma unroll
  for (int kk = 0; kk < 16; ++kk) {
    s16x8 a = *(const s16x8*)(qrow + kk * 32);
    s16x8 b = *(const s16x8*)(krow + kk * 32);
    acc = __builtin_amdgcn_mfma_f32_16x16x32_bf16(a, b, acc, 0, 0, 0);
  }

  if (l16 < 6) {  // n -> b0 KV rows
#pragma unroll
    for (int r = 0; r < 4; ++r) {
      int m = quad * 4 + r;
      if (m < 6)
        S[((size_t)b0 * 5 + head) * 36 + m * 6 + l16] = acc[r];
    }
  } else if (l16 >= 8 && l16 < 14) {  // n -> b1 KV rows
#pragma unroll
    for (int r = 0; r < 4; ++r) {
      int m = quad * 4 + r;
      if (m >= 8 && m < 14)
        S[((size_t)(b0 + 1) * 5 + head) * 36 + (m - 8) * 6 + (l16 - 8)] = acc[r];
    }
  }
}

// ---------------------------------------------------------------------------
// Per-batch: softmax(scores) -> cat@linW+linb -> softmax -> A;
// h = A@xg + gb1 -> PReLU -> BN1 -> H(bf16). Also store A (f32).
// ---------------------------------------------------------------------------
__global__ void batch_mid_kernel(const float* __restrict__ S, const bf16* __restrict__ XG,
                                 const float* __restrict__ linW, const float* __restrict__ linb,
                                 const float* __restrict__ gb1, const float* __restrict__ prelu,
                                 const float* __restrict__ g1, const float* __restrict__ b1,
                                 const float* __restrict__ m1, const float* __restrict__ v1,
                                 float* __restrict__ Afull, bf16* __restrict__ H) {
  int b = blockIdx.x, tid = threadIdx.x;  // 64 threads
  __shared__ float p[5][6][6];
  __shared__ float Ar[6][6];
  __shared__ float lw[30][6];
  __shared__ float lbv[6];
  __shared__ float sc1[6], sm1[6], sb1[6];

  if (tid < 30) {
    int k = tid / 6, c = tid % 6;
    const float* sp = S + ((size_t)b * 5 + k) * 36 + c * 6;
    float v[6], mx = sp[0];
#pragma unroll
    for (int d = 0; d < 6; ++d) { v[d] = sp[d]; mx = fmaxf(mx, v[d]); }
    float s = 0.f;
#pragma unroll
    for (int d = 0; d < 6; ++d) { v[d] = expf(v[d] - mx); s += v[d]; }
    float inv = 1.f / s;
#pragma unroll
    for (int d = 0; d < 6; ++d) p[k][c][d] = v[d] * inv;
#pragma unroll
    for (int j = 0; j < 6; ++j) lw[tid][j] = linW[tid * 6 + j];
  }
  if (tid < 6) {
    lbv[tid] = linb[tid];
    sc1[tid] = g1[tid] * rsqrtf(v1[tid] + 1e-5f);
    sm1[tid] = m1[tid];
    sb1[tid] = b1[tid];
  }
  __syncthreads();

  if (tid < 6) {
    int c = tid;
    float ap[6];
#pragma unroll
    for (int j = 0; j < 6; ++j) ap[j] = lbv[j];
    for (int k = 0; k < 5; ++k)
#pragma unroll
      for (int d = 0; d < 6; ++d) {
        float pv = p[k][c][d];
#pragma unroll
        for (int j = 0; j < 6; ++j) ap[j] += pv * lw[k * 6 + d][j];
      }
    float mx = ap[0];
#pragma unroll
    for (int j = 1; j < 6; ++j) mx = fmaxf(mx, ap[j]);
    float s = 0.f;
#pragma unroll
    for (int j = 0; j < 6; ++j) { ap[j] = expf(ap[j] - mx); s += ap[j]; }
    float inv = 1.f / s;
#pragma unroll
    for (int j = 0; j < 6; ++j) {
      float a = ap[j] * inv;
      Ar[c][j] = a;
      Afull[(size_t)b * 36 + c * 6 + j] = a;
    }
  }
  __syncthreads();

  float pa = prelu[0];
  for (int col = tid; col < 512; col += 64) {
    float xg[6];
#pragma unroll
    for (int d = 0; d < 6; ++d) xg[d] = s2f(((const short*)XG)[((size_t)b * 6 + d) * 512 + col]);
    float gbv = gb1[col];
#pragma unroll
    for (int c = 0; c < 6; ++c) {
      float h = gbv;
#pragma unroll
      for (int d = 0; d < 6; ++d) h += Ar[c][d] * xg[d];
      h = (h >= 0.f) ? h : pa * h;
      h = (h - sm1[c]) * sc1[c] + sb1[c];
      H[((size_t)b * 6 + c) * 512 + col] = __float2bfloat16(h);
    }
  }
}

// ---------------------------------------------------------------------------
// Per-batch: out(f32) = BN2(A @ hw + gb2)
// ---------------------------------------------------------------------------
__global__ void batch_out_kernel(const float* __restrict__ Afull, const bf16* __restrict__ HW,
                                 const float* __restrict__ gb2,
                                 const float* __restrict__ g2, const float* __restrict__ b2,
                                 const float* __restrict__ m2, const float* __restrict__ v2,
                                 float* __restrict__ out) {
  int b = blockIdx.x, tid = threadIdx.x;  // 64 threads
  __shared__ float Ar[36];
  __shared__ float sc[6], sm[6], sb[6];
  if (tid < 36) Ar[tid] = Afull[(size_t)b * 36 + tid];
  if (tid < 6) {
    sc[tid] = g2[tid] * rsqrtf(v2[tid] + 1e-5f);
    sm[tid] = m2[tid];
    sb[tid] = b2[tid];
  }
  __syncthreads();
  for (int col = tid; col < 256; col += 64) {
    float hw[6];
#pragma unroll
    for (int d = 0; d < 6; ++d) hw[d] = s2f(((const short*)HW)[((size_t)b * 6 + d) * 256 + col]);
    float gv = gb2[col];
#pragma unroll
    for (int c = 0; c < 6; ++c) {
      float o = gv;
#pragma unroll
      for (int d = 0; d < 6; ++d) o += Ar[c * 6 + d] * hw[d];
      o = (o - sm[c]) * sc[c] + sb[c];
      out[((size_t)b * 6 + c) * 256 + col] = o;
    }
  }
}

// ---------------------------------------------------------------------------
extern "C" void kernel_launch(void* const* d_in, const int* in_sizes, int n_in,
                              void* d_out, int out_size, void* d_ws, size_t ws_size,
                              hipStream_t stream) {
  const float* x    = (const float*)d_in[0];
  const float* aW1  = (const float*)d_in[1];
  const float* ab1  = (const float*)d_in[2];
  const float* aW2  = (const float*)d_in[3];
  const float* ab2  = (const float*)d_in[4];
  const float* linW = (const float*)d_in[5];
  const float* linb = (const float*)d_in[6];
  const float* gW1  = (const float*)d_in[7];
  const float* gb1  = (const float*)d_in[8];
  const float* gW2  = (const float*)d_in[9];
  const float* gb2  = (const float*)d_in[10];
  const float* prelu = (const float*)d_in[11];
  const float* bn1g = (const float*)d_in[12];
  const float* bn1b = (const float*)d_in[13];
  const float* bn1m = (const float*)d_in[14];
  const float* bn1v = (const float*)d_in[15];
  const float* bn2g = (const float*)d_in[16];
  const float* bn2b = (const float*)d_in[17];
  const float* bn2m = (const float*)d_in[18];
  const float* bn2v = (const float*)d_in[19];

  char* ws = (char*)d_ws;
  bf16* W1T  = (bf16*)(ws + 0);          // 5 x 512 x 1024
  bf16* W2T  = (bf16*)(ws + 5242880);    // 5 x 512 x 1024
  bf16* G1T  = (bf16*)(ws + 10485760);   // 512 x 1024
  bf16* G2T  = (bf16*)(ws + 11534336);   // 256 x 512
  float* S   = (float*)(ws + 11796480);  // 4096 x 5 x 36
  float* Af  = (float*)(ws + 14745600);  // 4096 x 36
  bf16* BufA = (bf16*)(ws + 15335424);   // 24576 x 512: Q(even head) / XG / HW
  bf16* BufB = (bf16*)(ws + 40501248);   // 24576 x 512: KV(even head) / H
  bf16* Xb   = (bf16*)(ws + 65667072);   // 24576 x 1024
  bf16* BufA2 = (bf16*)(ws + 115998720); // 24576 x 512: Q(odd head) / XG (big2)
  bf16* BufB2 = (bf16*)(ws + 141164544); // 24576 x 512: KV(odd head)
  const bool big  = ws_size >= 115998720ull;
  const bool big2 = ws_size >= 166330368ull;

  dim3 tb(32, 8);
  transpose_f2b<<<dim3(32, 16, 5), tb, 0, stream>>>(aW1, W1T, 1024, 512);
  transpose_f2b<<<dim3(32, 16, 5), tb, 0, stream>>>(aW2, W2T, 1024, 512);
  transpose_f2b<<<dim3(32, 16, 1), tb, 0, stream>>>(gW1, G1T, 1024, 512);
  transpose_f2b<<<dim3(16, 8, 1),  tb, 0, stream>>>(gW2, G2T, 512, 256);
  if (big) cvt_f32_bf16<<<12288, 256, 0, stream>>>(x, Xb, 3145728);

  if (big2) {
    // ---- head pairs {0,1}, {2,3}: z=4, 768 blocks = 3 full rounds ----
    for (int k = 0; k < 4; k += 2) {
      const size_t wo0 = (size_t)k * 524288, wo1 = (size_t)(k + 1) * 524288;
      GJob jq0{W1T + wo0, ab1, k * 512, BufA};
      GJob jk0{W2T + wo0, ab2, k * 512, BufB};
      GJob jq1{W1T + wo1, ab1, (k + 1) * 512, BufA2};
      GJob jk1{W2T + wo1, ab2, (k + 1) * 512, BufB2};
      gemm256_8ph<<<dim3(96, 2, 4), 512, 0, stream>>>(
          Xb, jq0, jk0, jq1, jk1, 24576, 512, 1024);
      scores_mfma2<<<dim3(512, 2), 256, 0, stream>>>(BufA, BufB, BufA2, BufB2, S, k);
    }
    // ---- final: head4 Q/KV + XG as z=3 (576 blocks) ----
    {
      const size_t wo4 = (size_t)4 * 524288;
      GJob jq4{W1T + wo4, ab1, 4 * 512, BufA};
      GJob jk4{W2T + wo4, ab2, 4 * 512, BufB};
      GJob jxg{G1T, nullptr, 0, BufA2};
      gemm256_8ph<<<dim3(96, 2, 3), 512, 0, stream>>>(
          Xb, jq4, jk4, jxg, jxg, 24576, 512, 1024);
      scores_mfma2<<<dim3(512, 1), 256, 0, stream>>>(BufA, BufB, BufA, BufB, S, 4);
    }
    // softmaxes + A + H (XG in BufA2; H -> BufB, KV4 dead)
    batch_mid_kernel<<<4096, 64, 0, stream>>>(S, BufA2, linW, linb, gb1, prelu,
                                              bn1g, bn1b, bn1m, bn1v, Af, BufB);
  } else {
    // ---- per head: Q,KV GEMM (z=2) then scores ----
    for (int k = 0; k < 5; ++k) {
      const bf16* w1 = W1T + (size_t)k * 524288;
      const bf16* w2 = W2T + (size_t)k * 524288;
      if (big) {
        GJob jq{w1, ab1, k * 512, BufA};
        GJob jk{w2, ab2, k * 512, BufB};
        gemm256_8ph<<<dim3(96, 2, 2), 512, 0, stream>>>(
            Xb, jq, jk, jq, jk, 24576, 512, 1024);
      } else {
        gemm_bt<1><<<dim3(192, 4, 2), 256, 0, stream>>>(
            x, w1, w2, ab1, ab2, k * 512, BufA, BufB, 24576, 512, 1024);
      }
      scores_mfma2<<<dim3(512, 1), 256, 0, stream>>>(BufA, BufB, BufA, BufB, S, k);
    }
    // XG = X @ gW1 (Q dead -> BufA)
    if (big) {
      GJob jxg{G1T, nullptr, 0, BufA};
      gemm256_8ph<<<dim3(96, 2, 1), 512, 0, stream>>>(
          Xb, jxg, jxg, jxg, jxg, 24576, 512, 1024);
    } else {
      gemm_bt<1><<<dim3(192, 4, 1), 256, 0, stream>>>(
          x, G1T, G1T, nullptr, nullptr, 0, BufA, BufA, 24576, 512, 1024);
    }
    batch_mid_kernel<<<4096, 64, 0, stream>>>(S, BufA, linW, linb, gb1, prelu,
                                              bn1g, bn1b, bn1m, bn1v, Af, BufB);
  }

  // HW = H @ gW2 -> BufA (legacy 128^2: (192,2)=384 blocks, better fill at N=256)
  gemm_bt<0><<<dim3(192, 2, 1), 256, 0, stream>>>(
      BufB, G2T, G2T, nullptr, nullptr, 0, BufA, BufA, 24576, 256, 512);

  batch_out_kernel<<<4096, 64, 0, stream>>>(Af, BufA, gb2, bn2g, bn2b, bn2m, bn2v,
                                            (float*)d_out);
}